// Round 11
// baseline (6235.336 us; speedup 1.0000x reference)
//
#include <hip/hip_runtime.h>
#include <math.h>

// LSTMModel: 2048 sequential steps, 2x LSTMCell(H=512), LN(64) front, fc(512->1).
// R10: MERGED layers. R9 proved weights resident (VGPR=36) yet step stuck ~2.9us ->
// remaining cost is sync fabric (MALL poll equilibrium). Merge L0+L1 into 128 blocks
// (4 L0-units + 4 L1-units each): ONE poll phase per step (h0(k-1) + h1(k-2)), since
// L1 step k-1 consumes h0(k-1) (same-step feed) - kills L1's separate h0 poll set and
// the second chained hop. Publishers emit one 16B packet per row per block (atomic
// visibility, 1:1 with x4 polls). pre prefetched 2 steps ahead into LDS ring by idle
// threads. Block-rotated poll offsets spread line traffic.

#define H      512
#define G4     2048
#define WIN    64
#define STEPS  2048
#define NBLK   128     // merged blocks: 4 L0-units + 4 L1-units each
#define TPB    512
#define POISON 0xFFFFFFFFu

typedef unsigned int u32x4 __attribute__((ext_vector_type(4)));

__device__ __forceinline__ float sigf(float x)     { return 1.0f / (1.0f + __expf(-x)); }
__device__ __forceinline__ float tanhfast(float x) { return 2.0f / (1.0f + __expf(-2.0f * x)) - 1.0f; }

// ---- agent-scope helpers (no "memory" clobber: volatile asms keep mutual order;
//      polled value IS the data; publishes are data-dependent) ----
__device__ __forceinline__ u32x4 ld4_sc01(const unsigned int* p) {
    u32x4 v;
    asm volatile("global_load_dwordx4 %0, %1, off sc0 sc1\n\ts_waitcnt vmcnt(0)"
                 : "=&v"(v) : "v"(p));
    return v;
}
__device__ __forceinline__ void st1_sc01(unsigned int* p, unsigned int v) {
    asm volatile("global_store_dword %0, %1, off sc0 sc1" :: "v"(p), "v"(v));
}
__device__ __forceinline__ bool ok4(u32x4 v) {
    return v.x != POISON && v.y != POISON && v.z != POISON && v.w != POISON;
}
__device__ __forceinline__ void lds_put4(float* dst, u32x4 v) {
    float4 f;
    f.x = __uint_as_float(v.x); f.y = __uint_as_float(v.y);
    f.z = __uint_as_float(v.z); f.w = __uint_as_float(v.w);
    *(float4*)dst = f;
}

// ---------------- LayerNorm over sliding windows (parallel over t) ----------------
__global__ void ln_kernel(const float* __restrict__ batch, const float* __restrict__ lnw,
                          const float* __restrict__ lnb, float* __restrict__ lnx) {
    int wave = threadIdx.x >> 6;
    int lane = threadIdx.x & 63;
    int t = blockIdx.x * 4 + wave;
    int src = t - 63 + lane;
    float v = (src >= 0) ? batch[src] : 0.0f;
    float s = v, ss = v * v;
    #pragma unroll
    for (int m = 32; m >= 1; m >>= 1) { s += __shfl_xor(s, m); ss += __shfl_xor(ss, m); }
    float mu   = s * (1.0f / 64.0f);
    float var  = ss * (1.0f / 64.0f) - mu * mu;
    float rstd = rsqrtf(var + 1e-5f);
    lnx[t * WIN + lane] = (v - mu) * rstd * lnw[lane] + lnb[lane];
}

// ---- precomp, UNIT-MAJOR layout: pre[t*2048 + unit*4 + gate] ----
__global__ __launch_bounds__(256) void precomp_kernel(
    const float* __restrict__ Wih0, const float* __restrict__ bih0,
    const float* __restrict__ bhh0, const float* __restrict__ lnx,
    float* __restrict__ pre) {
    __shared__ float Wt[64][65];
    __shared__ float Xt[64][64];
    int r0 = blockIdx.x * 64;
    int t0 = blockIdx.y * 64;
    for (int i = threadIdx.x; i < 4096; i += 256) Wt[i >> 6][i & 63] = Wih0[r0 * 64 + i];
    for (int i = threadIdx.x; i < 4096; i += 256) Xt[i >> 6][i & 63] = lnx[t0 * 64 + i];
    __syncthreads();
    int lane = threadIdx.x & 63;
    int wv   = threadIdx.x >> 6;
    int row  = r0 + lane;                      // gate-major: gate*512 + unit
    int oidx = (row & 511) * 4 + (row >> 9);   // unit-major: unit*4 + gate
    float bias = bih0[row] + bhh0[row];
    for (int j = 0; j < 16; ++j) {
        int tl = wv * 16 + j;
        float acc = bias;
        #pragma unroll 8
        for (int k = 0; k < 64; ++k) acc += Wt[lane][k] * Xt[tl][k];
        pre[(size_t)(t0 + tl) * G4 + oidx] = acc;
    }
}

// ---------------- persistent merged recurrent kernel ----------------
// Iteration k (k=0..2048): poll h0(k-1) & h1(k-2); compute+publish h0(k) [k<=2047]
// and h1(k-1) [k>=1]. h0u/h1u slot t = h(t). One poll phase, two barriers per iter.
__global__ __launch_bounds__(TPB) void recur_kernel(
    const float* __restrict__ Whh0,
    const float* __restrict__ Wih1, const float* __restrict__ Whh1,
    const float* __restrict__ bih1, const float* __restrict__ bhh1,
    const float* __restrict__ pre,
    unsigned int* h0u, unsigned int* h1u) { // [STEPS][H] histories, NaN-poisoned
    const int tid = threadIdx.x;
    const int s   = tid & 31;
    const int g   = tid >> 5;          // 16 lane-groups: unit_l = g>>2, gate = g&3
    const int b   = blockIdx.x;
    const int u0u = b * 4;             // unit base (both layers)
    const int u0f = b * 16;            // pre float base (unit-major)

    __shared__ float hA[H];            // h0(k-1)
    __shared__ float hB[H];            // h1(k-2)
    __shared__ float glds[32];         // [0:16) L0 gate accs, [16:32) L1 gate accs
    __shared__ float preb[4][16];      // pre ring, 2 steps ahead

    // one row per group, shared row index for all three matrices
    const int row = (g & 3) * H + u0u + (g >> 2);
    float w0[16], w1[16], w2[16];
    #pragma unroll
    for (int i = 0; i < 16; ++i) {
        w0[i] = Whh0[(size_t)row * H + i * 32 + s];
        w1[i] = Wih1[(size_t)row * H + i * 32 + s];
        w2[i] = Whh1[(size_t)row * H + i * 32 + s];
    }
    const float rb1 = bih1[row] + bhh1[row];
    float c0 = 0.0f, c1 = 0.0f;

    // prologue: pre(0), pre(1) into ring slots 0,1
    if (tid < 16)       preb[0][tid]      = pre[(size_t)0 * G4 + u0f + tid];
    else if (tid < 32)  preb[1][tid - 16] = pre[(size_t)1 * G4 + u0f + (tid - 16)];

    for (int k = 0; k <= STEPS; ++k) {
        // ---- fill phase: polls + pre prefetch ----
        if (tid < 128) {
            const int idx = (tid + b) & 127;             // block-rotated packet index
            if (k >= 1) {
                const unsigned int* p = h0u + (size_t)(k - 1) * H + idx * 4;
                u32x4 v;
                do { v = ld4_sc01(p); } while (!ok4(v));
                lds_put4(&hA[idx * 4], v);
            } else {
                *(float4*)&hA[idx * 4] = make_float4(0.f, 0.f, 0.f, 0.f);
            }
        } else if (tid < 256) {
            const int idx = ((tid - 128) + b) & 127;
            if (k >= 2) {
                const unsigned int* p = h1u + (size_t)(k - 2) * H + idx * 4;
                u32x4 v;
                do { v = ld4_sc01(p); } while (!ok4(v));
                lds_put4(&hB[idx * 4], v);
            } else {
                *(float4*)&hB[idx * 4] = make_float4(0.f, 0.f, 0.f, 0.f);
            }
        } else if (tid >= 496) {
            const int kk = k + 2;
            if (kk < STEPS)
                preb[kk & 3][tid - 496] = pre[(size_t)kk * G4 + u0f + (tid - 496)];
        }
        __syncthreads();

        // ---- dual dot: L0 row (h0 taps) and L1 row (h0 + h1 taps) ----
        float a0 = 0.0f, a1 = 0.0f;
        #pragma unroll
        for (int i = 0; i < 16; ++i) {
            float xa = hA[i * 32 + s];
            a0 += w0[i] * xa;
            a1 += w1[i] * xa + w2[i] * hB[i * 32 + s];
        }
        #pragma unroll
        for (int m = 16; m >= 1; m >>= 1) {
            a0 += __shfl_xor(a0, m);
            a1 += __shfl_xor(a1, m);
        }
        if (s == 0) { glds[g] = a0; glds[16 + g] = a1 + rb1; }
        __syncthreads();

        // ---- finalize: tid 0-3 -> L0 unit, tid 4-7 -> L1 unit ----
        if (tid < 4) {
            if (k < STEPS) {
                const float* pb = preb[k & 3];
                const int j = tid * 4;
                float iv = sigf(glds[j + 0] + pb[j + 0]);
                float fv = sigf(glds[j + 1] + pb[j + 1]);
                float gv = tanhfast(glds[j + 2] + pb[j + 2]);
                float ov = sigf(glds[j + 3] + pb[j + 3]);
                c0 = fv * c0 + iv * gv;
                float h = ov * tanhfast(c0);
                st1_sc01(h0u + (size_t)k * H + u0u + tid, __float_as_uint(h));
            }
        } else if (tid < 8) {
            if (k >= 1) {
                const int j = 16 + (tid - 4) * 4;
                float iv = sigf(glds[j + 0]);
                float fv = sigf(glds[j + 1]);
                float gv = tanhfast(glds[j + 2]);
                float ov = sigf(glds[j + 3]);
                c1 = fv * c1 + iv * gv;
                float h = ov * tanhfast(c1);
                st1_sc01(h1u + (size_t)(k - 1) * H + u0u + (tid - 4), __float_as_uint(h));
            }
        }
    }
}

// ---------------- out[t] = fc(relu(h1(t))) from the h1 history ----------------
__global__ __launch_bounds__(TPB) void reduce_out(
    const unsigned int* __restrict__ h1u, const float* __restrict__ fcw,
    const float* __restrict__ fcb, float* __restrict__ out) {
    int t = blockIdx.x;
    int tid = threadIdx.x;               // 512 threads
    float h = __uint_as_float(h1u[(size_t)t * H + tid]);
    float v = fmaxf(h, 0.0f) * fcw[tid];
    #pragma unroll
    for (int m = 32; m >= 1; m >>= 1) v += __shfl_xor(v, m);
    __shared__ float ws8[8];
    if ((tid & 63) == 0) ws8[tid >> 6] = v;
    __syncthreads();
    if (tid == 0) {
        float ssum = 0.0f;
        #pragma unroll
        for (int i = 0; i < 8; ++i) ssum += ws8[i];
        out[t] = ssum + fcb[0];
    }
}

extern "C" void kernel_launch(void* const* d_in, const int* in_sizes, int n_in,
                              void* d_out, int out_size, void* d_ws, size_t ws_size,
                              hipStream_t stream) {
    const float* batch = (const float*)d_in[0];
    const float* Wih0  = (const float*)d_in[1];
    const float* Whh0  = (const float*)d_in[2];
    const float* bih0  = (const float*)d_in[3];
    const float* bhh0  = (const float*)d_in[4];
    const float* Wih1  = (const float*)d_in[5];
    const float* Whh1  = (const float*)d_in[6];
    const float* bih1  = (const float*)d_in[7];
    const float* bhh1  = (const float*)d_in[8];
    const float* lnw   = (const float*)d_in[9];
    const float* lnb   = (const float*)d_in[10];
    const float* fcw   = (const float*)d_in[11];
    const float* fcb   = (const float*)d_in[12];
    float* out = (float*)d_out;

    // workspace layout (~25 MB)
    float*        ws   = (float*)d_ws;
    float*        pre  = ws;                                   // 2048*2048 (16 MB)
    float*        lnx  = pre + (size_t)STEPS * G4;             // 2048*64
    unsigned int* h0u  = (unsigned int*)(lnx + (size_t)STEPS * WIN);  // 2048*512
    unsigned int* h1u  = h0u + (size_t)STEPS * H;              // 2048*512

    // poison both h histories (NaN pattern); initial states via k<1/k<2 zero branches
    (void)hipMemsetAsync(h0u, 0xFF, (size_t)2 * STEPS * H * sizeof(unsigned int), stream);

    ln_kernel<<<dim3(STEPS / 4), dim3(256), 0, stream>>>(batch, lnw, lnb, lnx);
    precomp_kernel<<<dim3(G4 / 64, STEPS / 64), dim3(256), 0, stream>>>(Wih0, bih0, bhh0, lnx, pre);
    recur_kernel<<<dim3(NBLK), dim3(TPB), 0, stream>>>(Whh0, Wih1, Whh1, bih1, bhh1,
                                                       pre, h0u, h1u);
    reduce_out<<<dim3(STEPS), dim3(TPB), 0, stream>>>(h1u, fcw, fcb, out);
}